// Round 1
// baseline (2068.722 us; speedup 1.0000x reference)
//
#include <hip/hip_runtime.h>

#define NNODES 50000
#define NEDGES 600000
#define DIM 128

// ---------------------------------------------------------------------------
// Kernel 1: zero the two accumulator arrays (denom, wnum), each [N, D] f32.
// ---------------------------------------------------------------------------
__global__ __launch_bounds__(256) void k_init(float* __restrict__ denom,
                                              float* __restrict__ wnum) {
    int i = blockIdx.x * 256 + threadIdx.x;   // over N*D/4 float4s (exact)
    float4 z = make_float4(0.f, 0.f, 0.f, 0.f);
    reinterpret_cast<float4*>(denom)[i] = z;
    reinterpret_cast<float4*>(wnum)[i]  = z;
}

// ---------------------------------------------------------------------------
// Kernel 2: single edge pass.
//   m = node_feats[src] + edge_feats[e]
//   p = exp(m)            (no max-subtraction needed: |m| <~ 9, f32-safe;
//                          softmax is shift-invariant so result is identical)
//   denom[dst] += p ;  wnum[dst] += m*p
// One thread = 4 channels of one edge (float4).
// ---------------------------------------------------------------------------
__global__ __launch_bounds__(256) void k_edge(
    const float* __restrict__ nf, const float* __restrict__ ef,
    const int* __restrict__ src, const int* __restrict__ dst,
    float* __restrict__ denom, float* __restrict__ wnum)
{
    int idx = blockIdx.x * 256 + threadIdx.x;     // < NEDGES*32 (exact grid)
    int e = idx >> 5;
    int c = (idx & 31) << 2;
    int s  = src[e];
    int dn = dst[e];
    const float4 a = *reinterpret_cast<const float4*>(&nf[(size_t)s * DIM + c]);
    const float4 b = *reinterpret_cast<const float4*>(&ef[(size_t)e * DIM + c]);
    float m0 = a.x + b.x, m1 = a.y + b.y, m2 = a.z + b.z, m3 = a.w + b.w;
    float p0 = __expf(m0), p1 = __expf(m1), p2 = __expf(m2), p3 = __expf(m3);
    float* dd = &denom[dn * DIM + c];
    float* ww = &wnum[dn * DIM + c];
    unsafeAtomicAdd(dd + 0, p0);
    unsafeAtomicAdd(dd + 1, p1);
    unsafeAtomicAdd(dd + 2, p2);
    unsafeAtomicAdd(dd + 3, p3);
    unsafeAtomicAdd(ww + 0, m0 * p0);
    unsafeAtomicAdd(ww + 1, m1 * p1);
    unsafeAtomicAdd(ww + 2, m2 * p2);
    unsafeAtomicAdd(ww + 3, m3 * p3);
}

// ---------------------------------------------------------------------------
// Kernel 3: fused finalize.
//   agg = denom>0 ? wnum/denom : 0        (empty nodes -> agg = 0, matches ref)
//   h   = relu(agg @ W^T + b)
//   out = h * scale + node_feats
// W^T staged in LDS as Wt[k][j] (row stride 132 floats: 16B-aligned b128 reads,
// conflict-free since a 32-lane group covers a full contiguous 128-dword row).
// Block: 256 threads; per group-iter 16 nodes; each thread computes 4 output
// channels for 2 nodes (amortizes the Wt ds_read_b128 over 8 FMAs).
// ---------------------------------------------------------------------------
#define GNODES 16
#define GROUPS 4
#define NODES_PER_BLOCK (GNODES * GROUPS)

__global__ __launch_bounds__(256) void k_final(
    const float* __restrict__ denom, const float* __restrict__ wnum,
    const float* __restrict__ W, const float* __restrict__ bias,
    const float* __restrict__ scale, const float* __restrict__ nf,
    float* __restrict__ out)
{
    __shared__ float Wt[DIM][132];      // 67.6 KB
    __shared__ float aggS[GNODES][132]; // 8.4 KB  (132 stride: 4 active rows
                                        //  per wave land in distinct banks)
    const int t = threadIdx.x;

    // Stage W transposed: Wt[k][j] = W[j*128 + k]
    for (int i = t; i < DIM * DIM; i += 256) {
        Wt[i & 127][i >> 7] = W[i];
    }

    const int j4 = (t & 31) << 2;                 // output-channel base
    const float4 b4 = *reinterpret_cast<const float4*>(&bias[j4]);
    const float4 s4 = *reinterpret_cast<const float4*>(&scale[j4]);
    const int nl2 = (t >> 5) << 1;                // node pair within group

    int base = blockIdx.x * NODES_PER_BLOCK;
    for (int g = 0; g < GROUPS; ++g, base += GNODES) {
        __syncthreads();  // Wt ready (g==0); aggS readers done (g>0)

        // Load agg for GNODES nodes into LDS: 2048 floats, 8 per thread.
        {
            int f  = t << 3;          // 0..2047 step 8 (stays in one node row)
            int nl = f >> 7;
            int k  = f & 127;
            int n  = base + nl;
            if (n < NNODES) {
                const float4* dp = reinterpret_cast<const float4*>(&denom[(size_t)n * DIM + k]);
                const float4* wp = reinterpret_cast<const float4*>(&wnum[(size_t)n * DIM + k]);
#pragma unroll
                for (int q = 0; q < 2; ++q) {
                    float4 d = dp[q], w = wp[q];
                    float4 v;
                    v.x = d.x > 0.f ? w.x / d.x : 0.f;
                    v.y = d.y > 0.f ? w.y / d.y : 0.f;
                    v.z = d.z > 0.f ? w.z / d.z : 0.f;
                    v.w = d.w > 0.f ? w.w / d.w : 0.f;
                    *reinterpret_cast<float4*>(&aggS[nl][k + 4 * q]) = v;
                }
            } else {
                float4 z = make_float4(0.f, 0.f, 0.f, 0.f);
                *reinterpret_cast<float4*>(&aggS[nl][k])     = z;
                *reinterpret_cast<float4*>(&aggS[nl][k + 4]) = z;
            }
        }
        __syncthreads();

        // h[j] = bias[j] + sum_k agg[k] * W[j][k]
        float4 accA = b4, accB = b4;
        const float* arA = aggS[nl2];
        const float* arB = aggS[nl2 + 1];
#pragma unroll 8
        for (int k = 0; k < DIM; ++k) {
            const float4 w = *reinterpret_cast<const float4*>(&Wt[k][j4]);
            float aA = arA[k], aB = arB[k];
            accA.x = fmaf(aA, w.x, accA.x);
            accA.y = fmaf(aA, w.y, accA.y);
            accA.z = fmaf(aA, w.z, accA.z);
            accA.w = fmaf(aA, w.w, accA.w);
            accB.x = fmaf(aB, w.x, accB.x);
            accB.y = fmaf(aB, w.y, accB.y);
            accB.z = fmaf(aB, w.z, accB.z);
            accB.w = fmaf(aB, w.w, accB.w);
        }

        const int nA = base + nl2;
        const int nB = nA + 1;
        if (nA < NNODES) {
            float4 r = *reinterpret_cast<const float4*>(&nf[(size_t)nA * DIM + j4]);
            float4 o;
            o.x = fmaxf(accA.x, 0.f) * s4.x + r.x;
            o.y = fmaxf(accA.y, 0.f) * s4.y + r.y;
            o.z = fmaxf(accA.z, 0.f) * s4.z + r.z;
            o.w = fmaxf(accA.w, 0.f) * s4.w + r.w;
            *reinterpret_cast<float4*>(&out[(size_t)nA * DIM + j4]) = o;
        }
        if (nB < NNODES) {
            float4 r = *reinterpret_cast<const float4*>(&nf[(size_t)nB * DIM + j4]);
            float4 o;
            o.x = fmaxf(accB.x, 0.f) * s4.x + r.x;
            o.y = fmaxf(accB.y, 0.f) * s4.y + r.y;
            o.z = fmaxf(accB.z, 0.f) * s4.z + r.z;
            o.w = fmaxf(accB.w, 0.f) * s4.w + r.w;
            *reinterpret_cast<float4*>(&out[(size_t)nB * DIM + j4]) = o;
        }
    }
}

// ---------------------------------------------------------------------------
extern "C" void kernel_launch(void* const* d_in, const int* in_sizes, int n_in,
                              void* d_out, int out_size, void* d_ws, size_t ws_size,
                              hipStream_t stream) {
    const float* nf  = (const float*)d_in[0];  // node_feats [N, D]
    const float* ef  = (const float*)d_in[1];  // edge_feats [E, D]
    const float* W   = (const float*)d_in[2];  // mlp_w [D, D]
    const float* b   = (const float*)d_in[3];  // mlp_b [D]
    const float* sc  = (const float*)d_in[4];  // scale [D]
    const int*   src = (const int*)d_in[5];    // [E]
    const int*   dst = (const int*)d_in[6];    // [E]
    float* out = (float*)d_out;

    float* denom = (float*)d_ws;                       // [N, D]
    float* wnum  = denom + (size_t)NNODES * DIM;       // [N, D]

    // 1) zero accumulators (re-done every call: deterministic, ws is poisoned)
    k_init<<<(NNODES * DIM / 4) / 256, 256, 0, stream>>>(denom, wnum);

    // 2) one pass over all edges (float4 per thread -> E*32 threads, exact)
    k_edge<<<(NEDGES * 32) / 256, 256, 0, stream>>>(nf, ef, src, dst, denom, wnum);

    // 3) fused agg/MLP/LayerScale/residual
    k_final<<<(NNODES + NODES_PER_BLOCK - 1) / NODES_PER_BLOCK, 256, 0, stream>>>(
        denom, wnum, W, b, sc, nf, out);
}

// Round 2
// 274.497 us; speedup vs baseline: 7.5364x; 7.5364x over previous
//
#include <hip/hip_runtime.h>

#define NNODES 50000
#define NEDGES 600000
#define DIM 128

// ---------------------------------------------------------------------------
// ws layout:  pairs [E] int2 (8B-aligned, first) | deg [N] | offs [N+1] | cursor [N]
// ---------------------------------------------------------------------------

// Zero the degree array.
__global__ __launch_bounds__(256) void k_zero(int* __restrict__ deg) {
    int i = blockIdx.x * 256 + threadIdx.x;
    if (i < NNODES) deg[i] = 0;
}

// Histogram destinations. 600K int atomics over 200 KB — cheap.
__global__ __launch_bounds__(256) void k_count(const int* __restrict__ dst,
                                               int* __restrict__ deg) {
    int e = blockIdx.x * 256 + threadIdx.x;
    if (e < NEDGES) atomicAdd(&deg[dst[e]], 1);
}

// Single-block exclusive scan of deg -> offs[N+1]; also cursor[i] = offs[i].
// 1024 threads = 16 waves; wave-level shfl scan + 16-partial scan per chunk.
__global__ __launch_bounds__(1024) void k_scan(const int* __restrict__ deg,
                                               int* __restrict__ offs,
                                               int* __restrict__ cursor) {
    __shared__ int wsum[16];
    __shared__ int carry_s;
    const int t = threadIdx.x, lane = t & 63, wid = t >> 6;
    if (t == 0) carry_s = 0;
    __syncthreads();
    for (int base = 0; base < NNODES; base += 1024) {
        int i = base + t;
        int v = (i < NNODES) ? deg[i] : 0;
        // wave-inclusive scan
        int sc = v;
        #pragma unroll
        for (int off = 1; off < 64; off <<= 1) {
            int u = __shfl_up(sc, off);
            if (lane >= off) sc += u;
        }
        if (lane == 63) wsum[wid] = sc;
        __syncthreads();                       // wsum raw ready; carry_s stable
        int carry = carry_s;
        if (t < 16) {                          // wave 0: serial partial scan
            int s = 0;
            for (int k = 0; k <= t; ++k) s += wsum[k];
            wsum[t] = s;                       // lockstep: reads precede writes
        }
        __syncthreads();                       // wsum inclusive ready
        int woff = wid ? wsum[wid - 1] : 0;
        int incl = carry + woff + sc;
        if (i < NNODES) {
            offs[i + 1] = incl;
            cursor[i]   = incl - v;            // exclusive start
        }
        if (t == 1023) carry_s = carry + wsum[15];
        __syncthreads();                       // carry updated, wsum consumed
    }
    if (t == 0) offs[0] = 0;
}

// Scatter edges into CSR buckets: pairs[pos] = (edge_id, src[edge_id]).
__global__ __launch_bounds__(256) void k_scatter(const int* __restrict__ src,
                                                 const int* __restrict__ dst,
                                                 int* __restrict__ cursor,
                                                 int2* __restrict__ pairs) {
    int e = blockIdx.x * 256 + threadIdx.x;
    if (e < NEDGES) {
        int pos = atomicAdd(&cursor[dst[e]], 1);
        pairs[pos] = make_int2(e, src[e]);
    }
}

// ---------------------------------------------------------------------------
// One wave per node. Lanes split 32/32 over two edges per iteration:
// half h = lane>>5 takes edge (it+h); each half-wave reads a full coalesced
// 512B ef row + nf row (float4 per lane, c = 4*(lane&31)). Accumulate
// denom += exp(m), wnum += m*exp(m) in registers (softmax shift-invariance:
// skipping the segment-max is exact for the final ratio, |m| <~ 9 is f32-safe).
// Cross-half reduce with shfl_xor(32); lanes 0..31 write agg = wnum/denom.
// ---------------------------------------------------------------------------
__global__ __launch_bounds__(256) void k_agg(
    const float* __restrict__ nf, const float* __restrict__ ef,
    const int* __restrict__ offs, const int2* __restrict__ pairs,
    float* __restrict__ agg)
{
    const int wid = threadIdx.x >> 6, lane = threadIdx.x & 63;
    const int n = blockIdx.x * 4 + wid;
    if (n >= NNODES) return;
    const int beg = offs[n], end = offs[n + 1];
    const int half = lane >> 5;
    const int c = (lane & 31) << 2;
    float d0 = 0.f, d1 = 0.f, d2 = 0.f, d3 = 0.f;
    float w0 = 0.f, w1 = 0.f, w2 = 0.f, w3 = 0.f;
    #pragma unroll 2
    for (int it = beg; it < end; it += 2) {
        int idx = it + half;
        if (idx < end) {
            int2 pr = pairs[idx];
            const float4 a = *reinterpret_cast<const float4*>(&nf[(size_t)pr.y * DIM + c]);
            const float4 b = *reinterpret_cast<const float4*>(&ef[(size_t)pr.x * DIM + c]);
            float m0 = a.x + b.x, m1 = a.y + b.y, m2 = a.z + b.z, m3 = a.w + b.w;
            float p0 = __expf(m0), p1 = __expf(m1), p2 = __expf(m2), p3 = __expf(m3);
            d0 += p0; d1 += p1; d2 += p2; d3 += p3;
            w0 = fmaf(m0, p0, w0); w1 = fmaf(m1, p1, w1);
            w2 = fmaf(m2, p2, w2); w3 = fmaf(m3, p3, w3);
        }
    }
    d0 += __shfl_xor(d0, 32); d1 += __shfl_xor(d1, 32);
    d2 += __shfl_xor(d2, 32); d3 += __shfl_xor(d3, 32);
    w0 += __shfl_xor(w0, 32); w1 += __shfl_xor(w1, 32);
    w2 += __shfl_xor(w2, 32); w3 += __shfl_xor(w3, 32);
    if (half == 0) {
        float4 v;
        v.x = d0 > 0.f ? w0 / d0 : 0.f;
        v.y = d1 > 0.f ? w1 / d1 : 0.f;
        v.z = d2 > 0.f ? w2 / d2 : 0.f;
        v.w = d3 > 0.f ? w3 / d3 : 0.f;
        *reinterpret_cast<float4*>(&agg[(size_t)n * DIM + c]) = v;
    }
}

// ---------------------------------------------------------------------------
// Fused finalize: h = relu(agg @ W^T + b); out = h*scale + nf.
// W^T staged in LDS (stride 132); 16 nodes per group-iter, 4 groups per block.
// ---------------------------------------------------------------------------
#define GNODES 16
#define GROUPS 4
#define NODES_PER_BLOCK (GNODES * GROUPS)

__global__ __launch_bounds__(256) void k_final(
    const float* __restrict__ agg,
    const float* __restrict__ W, const float* __restrict__ bias,
    const float* __restrict__ scale, const float* __restrict__ nf,
    float* __restrict__ out)
{
    __shared__ float Wt[DIM][132];      // 66 KB
    __shared__ float aggS[GNODES][132]; // 8.4 KB
    const int t = threadIdx.x;

    for (int i = t; i < DIM * DIM; i += 256) {
        Wt[i & 127][i >> 7] = W[i];     // Wt[k][j] = W[j][k]
    }

    const int j4 = (t & 31) << 2;
    const float4 b4 = *reinterpret_cast<const float4*>(&bias[j4]);
    const float4 s4 = *reinterpret_cast<const float4*>(&scale[j4]);
    const int nl2 = (t >> 5) << 1;

    int base = blockIdx.x * NODES_PER_BLOCK;
    for (int g = 0; g < GROUPS; ++g, base += GNODES) {
        __syncthreads();

        {   // stage agg rows for GNODES nodes: 8 floats per thread
            int f  = t << 3;
            int nl = f >> 7;
            int k  = f & 127;
            int n  = base + nl;
            if (n < NNODES) {
                const float4* ap = reinterpret_cast<const float4*>(&agg[(size_t)n * DIM + k]);
                *reinterpret_cast<float4*>(&aggS[nl][k])     = ap[0];
                *reinterpret_cast<float4*>(&aggS[nl][k + 4]) = ap[1];
            } else {
                float4 z = make_float4(0.f, 0.f, 0.f, 0.f);
                *reinterpret_cast<float4*>(&aggS[nl][k])     = z;
                *reinterpret_cast<float4*>(&aggS[nl][k + 4]) = z;
            }
        }
        __syncthreads();

        float4 accA = b4, accB = b4;
        const float* arA = aggS[nl2];
        const float* arB = aggS[nl2 + 1];
        #pragma unroll 8
        for (int k = 0; k < DIM; ++k) {
            const float4 w = *reinterpret_cast<const float4*>(&Wt[k][j4]);
            float aA = arA[k], aB = arB[k];
            accA.x = fmaf(aA, w.x, accA.x);
            accA.y = fmaf(aA, w.y, accA.y);
            accA.z = fmaf(aA, w.z, accA.z);
            accA.w = fmaf(aA, w.w, accA.w);
            accB.x = fmaf(aB, w.x, accB.x);
            accB.y = fmaf(aB, w.y, accB.y);
            accB.z = fmaf(aB, w.z, accB.z);
            accB.w = fmaf(aB, w.w, accB.w);
        }

        const int nA = base + nl2;
        const int nB = nA + 1;
        if (nA < NNODES) {
            float4 r = *reinterpret_cast<const float4*>(&nf[(size_t)nA * DIM + j4]);
            float4 o;
            o.x = fmaxf(accA.x, 0.f) * s4.x + r.x;
            o.y = fmaxf(accA.y, 0.f) * s4.y + r.y;
            o.z = fmaxf(accA.z, 0.f) * s4.z + r.z;
            o.w = fmaxf(accA.w, 0.f) * s4.w + r.w;
            *reinterpret_cast<float4*>(&out[(size_t)nA * DIM + j4]) = o;
        }
        if (nB < NNODES) {
            float4 r = *reinterpret_cast<const float4*>(&nf[(size_t)nB * DIM + j4]);
            float4 o;
            o.x = fmaxf(accB.x, 0.f) * s4.x + r.x;
            o.y = fmaxf(accB.y, 0.f) * s4.y + r.y;
            o.z = fmaxf(accB.z, 0.f) * s4.z + r.z;
            o.w = fmaxf(accB.w, 0.f) * s4.w + r.w;
            *reinterpret_cast<float4*>(&out[(size_t)nB * DIM + j4]) = o;
        }
    }
}

// ---------------------------------------------------------------------------
extern "C" void kernel_launch(void* const* d_in, const int* in_sizes, int n_in,
                              void* d_out, int out_size, void* d_ws, size_t ws_size,
                              hipStream_t stream) {
    const float* nf  = (const float*)d_in[0];
    const float* ef  = (const float*)d_in[1];
    const float* W   = (const float*)d_in[2];
    const float* b   = (const float*)d_in[3];
    const float* sc  = (const float*)d_in[4];
    const int*   src = (const int*)d_in[5];
    const int*   dst = (const int*)d_in[6];
    float* out = (float*)d_out;

    int2* pairs  = (int2*)d_ws;                       // [E] (8B-aligned first)
    int*  deg    = (int*)(pairs + NEDGES);            // [N]
    int*  offs   = deg + NNODES;                      // [N+1]
    int*  cursor = offs + NNODES + 1;                 // [N]
    float* agg   = (float*)(cursor + NNODES + 3);     // [N, D] (16B-align pad)

    k_zero   <<<(NNODES + 255) / 256, 256, 0, stream>>>(deg);
    k_count  <<<(NEDGES + 255) / 256, 256, 0, stream>>>(dst, deg);
    k_scan   <<<1, 1024, 0, stream>>>(deg, offs, cursor);
    k_scatter<<<(NEDGES + 255) / 256, 256, 0, stream>>>(src, dst, cursor, pairs);
    k_agg    <<<(NNODES + 3) / 4, 256, 0, stream>>>(nf, ef, offs, pairs, agg);
    k_final  <<<(NNODES + NODES_PER_BLOCK - 1) / NODES_PER_BLOCK, 256, 0, stream>>>(
        agg, W, b, sc, nf, out);
}

// Round 3
// 221.260 us; speedup vs baseline: 9.3497x; 1.2406x over previous
//
#include <hip/hip_runtime.h>

#define NNODES 50000
#define NEDGES 600000
#define DIM 128

// ---------------------------------------------------------------------------
// ws layout: pairs [E] int2 | deg [N] | nbeg [N] | cursor [N] | gctr [1]
//            | agg [N*D] f32 (16B aligned)
// ---------------------------------------------------------------------------

// Zero degree array + the global range-allocation counter.
__global__ __launch_bounds__(256) void k_zero(int* __restrict__ deg,
                                              int* __restrict__ gctr) {
    int i = blockIdx.x * 256 + threadIdx.x;
    if (i < NNODES) deg[i] = 0;
    if (i == 0) *gctr = 0;
}

// Histogram destinations (600K int atomics over 200 KB of L2 — cheap).
__global__ __launch_bounds__(256) void k_count(const int* __restrict__ dst,
                                               int* __restrict__ deg) {
    int e = blockIdx.x * 256 + threadIdx.x;
    if (e < NEDGES) atomicAdd(&deg[dst[e]], 1);
}

// Range allocation WITHOUT a global scan: bucket order is irrelevant, only
// disjointness matters. Wave-level shfl inclusive scan of degrees; lane 63
// atomicAdds the wave total to gctr; every node gets base + exclusive prefix.
__global__ __launch_bounds__(256) void k_alloc(const int* __restrict__ deg,
                                               int* __restrict__ gctr,
                                               int* __restrict__ nbeg,
                                               int* __restrict__ cursor) {
    int i = blockIdx.x * 256 + threadIdx.x;
    int lane = threadIdx.x & 63;
    int v = (i < NNODES) ? deg[i] : 0;
    int sc = v;                                    // inclusive wave scan
    #pragma unroll
    for (int off = 1; off < 64; off <<= 1) {
        int u = __shfl_up(sc, off);
        if (lane >= off) sc += u;
    }
    int total = __shfl(sc, 63);
    int base = 0;
    if (lane == 63) base = atomicAdd(gctr, total);
    base = __shfl(base, 63);
    if (i < NNODES) {
        int b = base + (sc - v);                   // exclusive start
        nbeg[i]   = b;
        cursor[i] = b;
    }
}

// Scatter edges into CSR buckets: pairs[pos] = (edge_id, src[edge_id]).
__global__ __launch_bounds__(256) void k_scatter(const int* __restrict__ src,
                                                 const int* __restrict__ dst,
                                                 int* __restrict__ cursor,
                                                 int2* __restrict__ pairs) {
    int e = blockIdx.x * 256 + threadIdx.x;
    if (e < NEDGES) {
        int pos = atomicAdd(&cursor[dst[e]], 1);
        pairs[pos] = make_int2(e, src[e]);
    }
}

// ---------------------------------------------------------------------------
// One wave per node. Half-wave h = lane>>5 owns edges; float4 per lane over
// c = 4*(lane&31) covers one full coalesced 512B row per half-wave.
// Main loop: 4 edges/iteration (2 consecutive edges per half-wave, loads for
// both issued back-to-back -> 4-5 outstanding loads/lane for latency hiding).
// Softmax shift-invariance: denom += exp(m), wnum += m*exp(m) in registers,
// agg = wnum/denom. |m| <~ 9 so exp is f32-safe without max subtraction.
// ---------------------------------------------------------------------------
__global__ __launch_bounds__(256) void k_agg(
    const float* __restrict__ nf, const float* __restrict__ ef,
    const int* __restrict__ nbeg, const int* __restrict__ deg,
    const int2* __restrict__ pairs, float* __restrict__ agg)
{
    const int wid = threadIdx.x >> 6, lane = threadIdx.x & 63;
    const int n = blockIdx.x * 4 + wid;
    if (n >= NNODES) return;
    const int beg = nbeg[n];
    const int end = beg + deg[n];
    const int half = lane >> 5;
    const int c = (lane & 31) << 2;
    float d0 = 0.f, d1 = 0.f, d2 = 0.f, d3 = 0.f;
    float w0 = 0.f, w1 = 0.f, w2 = 0.f, w3 = 0.f;

    int it = beg;
    for (; it + 4 <= end; it += 4) {               // 4 edges per iteration
        int i0 = it + (half << 1);
        int2 pr0 = pairs[i0];
        int2 pr1 = pairs[i0 + 1];
        const float4 a0 = *reinterpret_cast<const float4*>(&nf[(size_t)pr0.y * DIM + c]);
        const float4 b0 = *reinterpret_cast<const float4*>(&ef[(size_t)pr0.x * DIM + c]);
        const float4 a1 = *reinterpret_cast<const float4*>(&nf[(size_t)pr1.y * DIM + c]);
        const float4 b1 = *reinterpret_cast<const float4*>(&ef[(size_t)pr1.x * DIM + c]);
        float m0 = a0.x + b0.x, m1 = a0.y + b0.y, m2 = a0.z + b0.z, m3 = a0.w + b0.w;
        float p0 = __expf(m0), p1 = __expf(m1), p2 = __expf(m2), p3 = __expf(m3);
        d0 += p0; d1 += p1; d2 += p2; d3 += p3;
        w0 = fmaf(m0, p0, w0); w1 = fmaf(m1, p1, w1);
        w2 = fmaf(m2, p2, w2); w3 = fmaf(m3, p3, w3);
        m0 = a1.x + b1.x; m1 = a1.y + b1.y; m2 = a1.z + b1.z; m3 = a1.w + b1.w;
        p0 = __expf(m0); p1 = __expf(m1); p2 = __expf(m2); p3 = __expf(m3);
        d0 += p0; d1 += p1; d2 += p2; d3 += p3;
        w0 = fmaf(m0, p0, w0); w1 = fmaf(m1, p1, w1);
        w2 = fmaf(m2, p2, w2); w3 = fmaf(m3, p3, w3);
    }
    for (; it < end; it += 2) {                    // tail (<= 3 edges)
        int idx = it + half;
        if (idx < end) {
            int2 pr = pairs[idx];
            const float4 a = *reinterpret_cast<const float4*>(&nf[(size_t)pr.y * DIM + c]);
            const float4 b = *reinterpret_cast<const float4*>(&ef[(size_t)pr.x * DIM + c]);
            float m0 = a.x + b.x, m1 = a.y + b.y, m2 = a.z + b.z, m3 = a.w + b.w;
            float p0 = __expf(m0), p1 = __expf(m1), p2 = __expf(m2), p3 = __expf(m3);
            d0 += p0; d1 += p1; d2 += p2; d3 += p3;
            w0 = fmaf(m0, p0, w0); w1 = fmaf(m1, p1, w1);
            w2 = fmaf(m2, p2, w2); w3 = fmaf(m3, p3, w3);
        }
    }

    d0 += __shfl_xor(d0, 32); d1 += __shfl_xor(d1, 32);
    d2 += __shfl_xor(d2, 32); d3 += __shfl_xor(d3, 32);
    w0 += __shfl_xor(w0, 32); w1 += __shfl_xor(w1, 32);
    w2 += __shfl_xor(w2, 32); w3 += __shfl_xor(w3, 32);
    if (half == 0) {
        float4 v;
        v.x = d0 > 0.f ? w0 / d0 : 0.f;
        v.y = d1 > 0.f ? w1 / d1 : 0.f;
        v.z = d2 > 0.f ? w2 / d2 : 0.f;
        v.w = d3 > 0.f ? w3 / d3 : 0.f;
        *reinterpret_cast<float4*>(&agg[(size_t)n * DIM + c]) = v;
    }
}

// ---------------------------------------------------------------------------
// Fused finalize: h = relu(agg @ W^T + b); out = h*scale + nf.
// W^T staged in LDS (stride 132); 16 nodes per group-iter, 4 groups per block.
// ---------------------------------------------------------------------------
#define GNODES 16
#define GROUPS 4
#define NODES_PER_BLOCK (GNODES * GROUPS)

__global__ __launch_bounds__(256) void k_final(
    const float* __restrict__ agg,
    const float* __restrict__ W, const float* __restrict__ bias,
    const float* __restrict__ scale, const float* __restrict__ nf,
    float* __restrict__ out)
{
    __shared__ float Wt[DIM][132];      // 66 KB
    __shared__ float aggS[GNODES][132]; // 8.4 KB
    const int t = threadIdx.x;

    for (int i = t; i < DIM * DIM; i += 256) {
        Wt[i & 127][i >> 7] = W[i];     // Wt[k][j] = W[j][k]
    }

    const int j4 = (t & 31) << 2;
    const float4 b4 = *reinterpret_cast<const float4*>(&bias[j4]);
    const float4 s4 = *reinterpret_cast<const float4*>(&scale[j4]);
    const int nl2 = (t >> 5) << 1;

    int base = blockIdx.x * NODES_PER_BLOCK;
    for (int g = 0; g < GROUPS; ++g, base += GNODES) {
        __syncthreads();

        {   // stage agg rows for GNODES nodes: 8 floats per thread
            int f  = t << 3;
            int nl = f >> 7;
            int k  = f & 127;
            int n  = base + nl;
            if (n < NNODES) {
                const float4* ap = reinterpret_cast<const float4*>(&agg[(size_t)n * DIM + k]);
                *reinterpret_cast<float4*>(&aggS[nl][k])     = ap[0];
                *reinterpret_cast<float4*>(&aggS[nl][k + 4]) = ap[1];
            } else {
                float4 z = make_float4(0.f, 0.f, 0.f, 0.f);
                *reinterpret_cast<float4*>(&aggS[nl][k])     = z;
                *reinterpret_cast<float4*>(&aggS[nl][k + 4]) = z;
            }
        }
        __syncthreads();

        float4 accA = b4, accB = b4;
        const float* arA = aggS[nl2];
        const float* arB = aggS[nl2 + 1];
        #pragma unroll 8
        for (int k = 0; k < DIM; ++k) {
            const float4 w = *reinterpret_cast<const float4*>(&Wt[k][j4]);
            float aA = arA[k], aB = arB[k];
            accA.x = fmaf(aA, w.x, accA.x);
            accA.y = fmaf(aA, w.y, accA.y);
            accA.z = fmaf(aA, w.z, accA.z);
            accA.w = fmaf(aA, w.w, accA.w);
            accB.x = fmaf(aB, w.x, accB.x);
            accB.y = fmaf(aB, w.y, accB.y);
            accB.z = fmaf(aB, w.z, accB.z);
            accB.w = fmaf(aB, w.w, accB.w);
        }

        const int nA = base + nl2;
        const int nB = nA + 1;
        if (nA < NNODES) {
            float4 r = *reinterpret_cast<const float4*>(&nf[(size_t)nA * DIM + j4]);
            float4 o;
            o.x = fmaxf(accA.x, 0.f) * s4.x + r.x;
            o.y = fmaxf(accA.y, 0.f) * s4.y + r.y;
            o.z = fmaxf(accA.z, 0.f) * s4.z + r.z;
            o.w = fmaxf(accA.w, 0.f) * s4.w + r.w;
            *reinterpret_cast<float4*>(&out[(size_t)nA * DIM + j4]) = o;
        }
        if (nB < NNODES) {
            float4 r = *reinterpret_cast<const float4*>(&nf[(size_t)nB * DIM + j4]);
            float4 o;
            o.x = fmaxf(accB.x, 0.f) * s4.x + r.x;
            o.y = fmaxf(accB.y, 0.f) * s4.y + r.y;
            o.z = fmaxf(accB.z, 0.f) * s4.z + r.z;
            o.w = fmaxf(accB.w, 0.f) * s4.w + r.w;
            *reinterpret_cast<float4*>(&out[(size_t)nB * DIM + j4]) = o;
        }
    }
}

// ---------------------------------------------------------------------------
extern "C" void kernel_launch(void* const* d_in, const int* in_sizes, int n_in,
                              void* d_out, int out_size, void* d_ws, size_t ws_size,
                              hipStream_t stream) {
    const float* nf  = (const float*)d_in[0];
    const float* ef  = (const float*)d_in[1];
    const float* W   = (const float*)d_in[2];
    const float* b   = (const float*)d_in[3];
    const float* sc  = (const float*)d_in[4];
    const int*   src = (const int*)d_in[5];
    const int*   dst = (const int*)d_in[6];
    float* out = (float*)d_out;

    int2* pairs  = (int2*)d_ws;                       // [E]
    int*  deg    = (int*)(pairs + NEDGES);            // [N]
    int*  nbeg   = deg + NNODES;                      // [N]
    int*  cursor = nbeg + NNODES;                     // [N]
    int*  gctr   = cursor + NNODES;                   // [1]
    float* agg   = (float*)(gctr + 3);                // [N, D] (16B-aligned)

    k_zero   <<<(NNODES + 255) / 256, 256, 0, stream>>>(deg, gctr);
    k_count  <<<(NEDGES + 255) / 256, 256, 0, stream>>>(dst, deg);
    k_alloc  <<<(NNODES + 255) / 256, 256, 0, stream>>>(deg, gctr, nbeg, cursor);
    k_scatter<<<(NEDGES + 255) / 256, 256, 0, stream>>>(src, dst, cursor, pairs);
    k_agg    <<<(NNODES + 3) / 4, 256, 0, stream>>>(nf, ef, nbeg, deg, pairs, agg);
    k_final  <<<(NNODES + NODES_PER_BLOCK - 1) / NODES_PER_BLOCK, 256, 0, stream>>>(
        agg, W, b, sc, nf, out);
}

// Round 4
// 218.490 us; speedup vs baseline: 9.4683x; 1.0127x over previous
//
#include <hip/hip_runtime.h>

#define NNODES 50000
#define NEDGES 600000
#define DIM 128

typedef float f32x4 __attribute__((ext_vector_type(4)));
typedef int   i32x2 __attribute__((ext_vector_type(2)));

// ---------------------------------------------------------------------------
// ws layout: pairs [E] int2 | deg [N] | nbeg [N] | cursor [N] | gctr [1]
//            | agg [N*D] f32 (16B aligned)
// ---------------------------------------------------------------------------

// Zero degree array + the global range-allocation counter.
__global__ __launch_bounds__(256) void k_zero(int* __restrict__ deg,
                                              int* __restrict__ gctr) {
    int i = blockIdx.x * 256 + threadIdx.x;
    if (i < NNODES) deg[i] = 0;
    if (i == 0) *gctr = 0;
}

// Histogram destinations (600K int atomics over 200 KB of L2 — cheap).
__global__ __launch_bounds__(256) void k_count(const int* __restrict__ dst,
                                               int* __restrict__ deg) {
    int e = blockIdx.x * 256 + threadIdx.x;
    if (e < NEDGES) atomicAdd(&deg[dst[e]], 1);
}

// Range allocation WITHOUT a global scan: bucket order is irrelevant, only
// disjointness matters. Wave-level shfl inclusive scan of degrees; lane 63
// atomicAdds the wave total to gctr; every node gets base + exclusive prefix.
__global__ __launch_bounds__(256) void k_alloc(const int* __restrict__ deg,
                                               int* __restrict__ gctr,
                                               int* __restrict__ nbeg,
                                               int* __restrict__ cursor) {
    int i = blockIdx.x * 256 + threadIdx.x;
    int lane = threadIdx.x & 63;
    int v = (i < NNODES) ? deg[i] : 0;
    int sc = v;                                    // inclusive wave scan
    #pragma unroll
    for (int off = 1; off < 64; off <<= 1) {
        int u = __shfl_up(sc, off);
        if (lane >= off) sc += u;
    }
    int total = __shfl(sc, 63);
    int base = 0;
    if (lane == 63) base = atomicAdd(gctr, total);
    base = __shfl(base, 63);
    if (i < NNODES) {
        int b = base + (sc - v);                   // exclusive start
        nbeg[i]   = b;
        cursor[i] = b;
    }
}

// Scatter edges into CSR buckets: pairs[pos] = (edge_id, src[edge_id]).
// pairs stays cacheable: k_agg reads it right after (4.8 MB, L3-resident).
__global__ __launch_bounds__(256) void k_scatter(const int* __restrict__ src,
                                                 const int* __restrict__ dst,
                                                 int* __restrict__ cursor,
                                                 int2* __restrict__ pairs) {
    int e = blockIdx.x * 256 + threadIdx.x;
    if (e < NEDGES) {
        int pos = atomicAdd(&cursor[dst[e]], 1);
        pairs[pos] = make_int2(e, src[e]);
    }
}

// ---------------------------------------------------------------------------
// One wave per node; half-wave h = lane>>5 owns edges; float4 per lane over
// c = 4*(lane&31) covers one full 512B row per half-wave.
// NT policy: ef (307 MB, zero reuse) and pairs are loaded NON-TEMPORAL so
// they don't evict nf (25.6 MB, ~12x reuse) from L2/LLC; nf loads stay
// cacheable; agg store is non-temporal (consumed much later by k_final).
// Softmax shift-invariance: denom += exp(m), wnum += m*exp(m) in registers,
// agg = wnum/denom. |m| <~ 9 so exp is f32-safe without max subtraction.
// ---------------------------------------------------------------------------
__global__ __launch_bounds__(256) void k_agg(
    const float* __restrict__ nf, const float* __restrict__ ef,
    const int* __restrict__ nbeg, const int* __restrict__ deg,
    const int2* __restrict__ pairs, float* __restrict__ agg)
{
    const int wid = threadIdx.x >> 6, lane = threadIdx.x & 63;
    const int n = blockIdx.x * 4 + wid;
    if (n >= NNODES) return;
    const int beg = nbeg[n];
    const int end = beg + deg[n];
    const int half = lane >> 5;
    const int c = (lane & 31) << 2;
    float d0 = 0.f, d1 = 0.f, d2 = 0.f, d3 = 0.f;
    float w0 = 0.f, w1 = 0.f, w2 = 0.f, w3 = 0.f;

    int it = beg;
    for (; it + 4 <= end; it += 4) {               // 4 edges per iteration
        int i0 = it + (half << 1);
        i32x2 pr0 = __builtin_nontemporal_load(
            reinterpret_cast<const i32x2*>(&pairs[i0]));
        i32x2 pr1 = __builtin_nontemporal_load(
            reinterpret_cast<const i32x2*>(&pairs[i0 + 1]));
        const f32x4 a0 = *reinterpret_cast<const f32x4*>(&nf[(size_t)pr0.y * DIM + c]);
        const f32x4 b0 = __builtin_nontemporal_load(
            reinterpret_cast<const f32x4*>(&ef[(size_t)pr0.x * DIM + c]));
        const f32x4 a1 = *reinterpret_cast<const f32x4*>(&nf[(size_t)pr1.y * DIM + c]);
        const f32x4 b1 = __builtin_nontemporal_load(
            reinterpret_cast<const f32x4*>(&ef[(size_t)pr1.x * DIM + c]));
        float m0 = a0.x + b0.x, m1 = a0.y + b0.y, m2 = a0.z + b0.z, m3 = a0.w + b0.w;
        float p0 = __expf(m0), p1 = __expf(m1), p2 = __expf(m2), p3 = __expf(m3);
        d0 += p0; d1 += p1; d2 += p2; d3 += p3;
        w0 = fmaf(m0, p0, w0); w1 = fmaf(m1, p1, w1);
        w2 = fmaf(m2, p2, w2); w3 = fmaf(m3, p3, w3);
        m0 = a1.x + b1.x; m1 = a1.y + b1.y; m2 = a1.z + b1.z; m3 = a1.w + b1.w;
        p0 = __expf(m0); p1 = __expf(m1); p2 = __expf(m2); p3 = __expf(m3);
        d0 += p0; d1 += p1; d2 += p2; d3 += p3;
        w0 = fmaf(m0, p0, w0); w1 = fmaf(m1, p1, w1);
        w2 = fmaf(m2, p2, w2); w3 = fmaf(m3, p3, w3);
    }
    for (; it < end; it += 2) {                    // tail (<= 3 edges)
        int idx = it + half;
        if (idx < end) {
            i32x2 pr = __builtin_nontemporal_load(
                reinterpret_cast<const i32x2*>(&pairs[idx]));
            const f32x4 a = *reinterpret_cast<const f32x4*>(&nf[(size_t)pr.y * DIM + c]);
            const f32x4 b = __builtin_nontemporal_load(
                reinterpret_cast<const f32x4*>(&ef[(size_t)pr.x * DIM + c]));
            float m0 = a.x + b.x, m1 = a.y + b.y, m2 = a.z + b.z, m3 = a.w + b.w;
            float p0 = __expf(m0), p1 = __expf(m1), p2 = __expf(m2), p3 = __expf(m3);
            d0 += p0; d1 += p1; d2 += p2; d3 += p3;
            w0 = fmaf(m0, p0, w0); w1 = fmaf(m1, p1, w1);
            w2 = fmaf(m2, p2, w2); w3 = fmaf(m3, p3, w3);
        }
    }

    d0 += __shfl_xor(d0, 32); d1 += __shfl_xor(d1, 32);
    d2 += __shfl_xor(d2, 32); d3 += __shfl_xor(d3, 32);
    w0 += __shfl_xor(w0, 32); w1 += __shfl_xor(w1, 32);
    w2 += __shfl_xor(w2, 32); w3 += __shfl_xor(w3, 32);
    if (half == 0) {
        f32x4 v;
        v.x = d0 > 0.f ? w0 / d0 : 0.f;
        v.y = d1 > 0.f ? w1 / d1 : 0.f;
        v.z = d2 > 0.f ? w2 / d2 : 0.f;
        v.w = d3 > 0.f ? w3 / d3 : 0.f;
        __builtin_nontemporal_store(v,
            reinterpret_cast<f32x4*>(&agg[(size_t)n * DIM + c]));
    }
}

// ---------------------------------------------------------------------------
// Fused finalize: h = relu(agg @ W^T + b); out = h*scale + nf.
// W^T staged in LDS (stride 132); 16 nodes per group-iter, 4 groups per block.
// out store is non-temporal (no consumer on device).
// ---------------------------------------------------------------------------
#define GNODES 16
#define GROUPS 4
#define NODES_PER_BLOCK (GNODES * GROUPS)

__global__ __launch_bounds__(256) void k_final(
    const float* __restrict__ agg,
    const float* __restrict__ W, const float* __restrict__ bias,
    const float* __restrict__ scale, const float* __restrict__ nf,
    float* __restrict__ out)
{
    __shared__ float Wt[DIM][132];      // 66 KB
    __shared__ float aggS[GNODES][132]; // 8.4 KB
    const int t = threadIdx.x;

    for (int i = t; i < DIM * DIM; i += 256) {
        Wt[i & 127][i >> 7] = W[i];     // Wt[k][j] = W[j][k]
    }

    const int j4 = (t & 31) << 2;
    const float4 b4 = *reinterpret_cast<const float4*>(&bias[j4]);
    const float4 s4 = *reinterpret_cast<const float4*>(&scale[j4]);
    const int nl2 = (t >> 5) << 1;

    int base = blockIdx.x * NODES_PER_BLOCK;
    for (int g = 0; g < GROUPS; ++g, base += GNODES) {
        __syncthreads();

        {   // stage agg rows for GNODES nodes: 8 floats per thread
            int f  = t << 3;
            int nl = f >> 7;
            int k  = f & 127;
            int n  = base + nl;
            if (n < NNODES) {
                const float4* ap = reinterpret_cast<const float4*>(&agg[(size_t)n * DIM + k]);
                *reinterpret_cast<float4*>(&aggS[nl][k])     = ap[0];
                *reinterpret_cast<float4*>(&aggS[nl][k + 4]) = ap[1];
            } else {
                float4 z = make_float4(0.f, 0.f, 0.f, 0.f);
                *reinterpret_cast<float4*>(&aggS[nl][k])     = z;
                *reinterpret_cast<float4*>(&aggS[nl][k + 4]) = z;
            }
        }
        __syncthreads();

        float4 accA = b4, accB = b4;
        const float* arA = aggS[nl2];
        const float* arB = aggS[nl2 + 1];
        #pragma unroll 8
        for (int k = 0; k < DIM; ++k) {
            const float4 w = *reinterpret_cast<const float4*>(&Wt[k][j4]);
            float aA = arA[k], aB = arB[k];
            accA.x = fmaf(aA, w.x, accA.x);
            accA.y = fmaf(aA, w.y, accA.y);
            accA.z = fmaf(aA, w.z, accA.z);
            accA.w = fmaf(aA, w.w, accA.w);
            accB.x = fmaf(aB, w.x, accB.x);
            accB.y = fmaf(aB, w.y, accB.y);
            accB.z = fmaf(aB, w.z, accB.z);
            accB.w = fmaf(aB, w.w, accB.w);
        }

        const int nA = base + nl2;
        const int nB = nA + 1;
        if (nA < NNODES) {
            float4 r = *reinterpret_cast<const float4*>(&nf[(size_t)nA * DIM + j4]);
            f32x4 o;
            o.x = fmaxf(accA.x, 0.f) * s4.x + r.x;
            o.y = fmaxf(accA.y, 0.f) * s4.y + r.y;
            o.z = fmaxf(accA.z, 0.f) * s4.z + r.z;
            o.w = fmaxf(accA.w, 0.f) * s4.w + r.w;
            __builtin_nontemporal_store(o,
                reinterpret_cast<f32x4*>(&out[(size_t)nA * DIM + j4]));
        }
        if (nB < NNODES) {
            float4 r = *reinterpret_cast<const float4*>(&nf[(size_t)nB * DIM + j4]);
            f32x4 o;
            o.x = fmaxf(accB.x, 0.f) * s4.x + r.x;
            o.y = fmaxf(accB.y, 0.f) * s4.y + r.y;
            o.z = fmaxf(accB.z, 0.f) * s4.z + r.z;
            o.w = fmaxf(accB.w, 0.f) * s4.w + r.w;
            __builtin_nontemporal_store(o,
                reinterpret_cast<f32x4*>(&out[(size_t)nB * DIM + j4]));
        }
    }
}

// ---------------------------------------------------------------------------
extern "C" void kernel_launch(void* const* d_in, const int* in_sizes, int n_in,
                              void* d_out, int out_size, void* d_ws, size_t ws_size,
                              hipStream_t stream) {
    const float* nf  = (const float*)d_in[0];
    const float* ef  = (const float*)d_in[1];
    const float* W   = (const float*)d_in[2];
    const float* b   = (const float*)d_in[3];
    const float* sc  = (const float*)d_in[4];
    const int*   src = (const int*)d_in[5];
    const int*   dst = (const int*)d_in[6];
    float* out = (float*)d_out;

    int2* pairs  = (int2*)d_ws;                       // [E]
    int*  deg    = (int*)(pairs + NEDGES);            // [N]
    int*  nbeg   = deg + NNODES;                      // [N]
    int*  cursor = nbeg + NNODES;                     // [N]
    int*  gctr   = cursor + NNODES;                   // [1]
    float* agg   = (float*)(gctr + 3);                // [N, D] (16B-aligned)

    k_zero   <<<(NNODES + 255) / 256, 256, 0, stream>>>(deg, gctr);
    k_count  <<<(NEDGES + 255) / 256, 256, 0, stream>>>(dst, deg);
    k_alloc  <<<(NNODES + 255) / 256, 256, 0, stream>>>(deg, gctr, nbeg, cursor);
    k_scatter<<<(NEDGES + 255) / 256, 256, 0, stream>>>(src, dst, cursor, pairs);
    k_agg    <<<(NNODES + 3) / 4, 256, 0, stream>>>(nf, ef, nbeg, deg, pairs, agg);
    k_final  <<<(NNODES + NODES_PER_BLOCK - 1) / NODES_PER_BLOCK, 256, 0, stream>>>(
        agg, W, b, sc, nf, out);
}